// Round 6
// baseline (1399.190 us; speedup 1.0000x reference)
//
#include <hip/hip_runtime.h>
#include <math.h>

// ---------------------------------------------------------------------------
// Kernel 1: fused conv1(3->32) + relu + conv2(32->32) + relu + maxpool4
// Output NHWC: P1[b][py][px][oc], 32x32 spatial, 32 ch.
// Block: 512 threads (8 waves), conv2 region 16x32, grid (32,128).
// Thread = 1 output pixel x 32 oc: acc[32] fits arch VGPRs (no AGPR tax).
// Window: 2 aligned ds_read_b64 per row (2-way banks = free) + 3 selects.
// Weights: wave-uniform s_load broadcast from repacked Wk2[tap*32+ci][oc].
// Maxpool 4x4: each 16-lane group holds one full pool window (shfl_xor 1/2/4/8).
// ---------------------------------------------------------------------------
__global__ __launch_bounds__(512, 4)
void k_conv12(const float* __restrict__ img, const float* __restrict__ w1,
              const float* __restrict__ b1, const float* __restrict__ Wk2,
              const float* __restrict__ b2, float* __restrict__ P1)
{
    __shared__ float simg[3 * 20 * 36 + 4];   // 2164 fl
    __shared__ float c1t[8 * 18 * 36];        // 5184 fl  (total ~29.4 KB)

    const int t  = threadIdx.x;               // 0..511
    const int bt = blockIdx.x;                // 0..31
    const int b  = blockIdx.y;
    const int ty = bt >> 2, tx = bt & 3;      // 8 row-tiles x 4 col-tiles
    const int oy = ty * 16, ox = tx * 32;

    // stage image tile [3][20][36], origin (oy-2, ox-2), zero-padded
    for (int i = t; i < 2160; i += 512) {
        const int ci = i / 720, r = i - ci * 720;
        const int yy = r / 36, xx = r - yy * 36;
        const int gy = oy - 2 + yy, gx = ox - 2 + xx;
        float v = 0.f;
        if ((unsigned)gy < 128u && (unsigned)gx < 128u)
            v = img[((b * 3 + ci) * 128 + gy) * 128 + gx];
        simg[i] = v;
    }

    const int wvu  = __builtin_amdgcn_readfirstlane(t >> 6);  // wave 0..7
    const int lane = t & 63;
    const int cell = wvu * 4 + (lane >> 4);   // pool cell 0..31 (4 rows x 8 cols)
    const int r_in = (lane >> 2) & 3, c_in = lane & 3;
    const int pyl  = cell >> 3, pxl = cell & 7;
    const int y    = pyl * 4 + r_in;          // conv2 out row 0..15
    const int x    = pxl * 4 + c_in;          // conv2 out col 0..31
    const int xb   = x & ~1;                  // aligned b64 base
    const bool sel = (x & 1) != 0;

    float acc[32];
    #pragma unroll
    for (int j = 0; j < 32; ++j) acc[j] = 0.f;

    #pragma unroll 1
    for (int p = 0; p < 4; ++p) {
        __syncthreads();   // simg ready (p=0) / prev conv2 reads done (p>0)

        // ---- conv1: wave computes channel p*8+wvu over 162 strips ----
        {
            const int ch = p * 8 + wvu;          // uniform -> s_load weights
            float w1r[27];
            #pragma unroll
            for (int q = 0; q < 27; ++q) w1r[q] = w1[ch * 27 + q];
            const float bb = b1[ch];

            #pragma unroll 1
            for (int it = 0; it < 3; ++it) {
                const int s = lane + it * 64;
                if (s < 162) {                   // 18 rows x 9 strips of 4 cols
                    const int yy = s / 9;
                    const int x0 = (s - yy * 9) * 4;
                    float a0[4] = {0.f, 0.f, 0.f, 0.f};
                    #pragma unroll
                    for (int ci = 0; ci < 3; ++ci)
                        #pragma unroll
                        for (int dy = 0; dy < 3; ++dy) {
                            const float* rp = &simg[ci * 720 + (yy + dy) * 36 + x0];
                            const float4 v4 = *(const float4*)rp;
                            const float2 v2 = *(const float2*)(rp + 4);
                            const float in6[6] = {v4.x, v4.y, v4.z, v4.w, v2.x, v2.y};
                            const int wb = ci * 9 + dy * 3;
                            #pragma unroll
                            for (int c = 0; c < 4; ++c) {
                                a0[c] = fmaf(w1r[wb],     in6[c],     a0[c]);
                                a0[c] = fmaf(w1r[wb + 1], in6[c + 1], a0[c]);
                                a0[c] = fmaf(w1r[wb + 2], in6[c + 2], a0[c]);
                            }
                        }
                    const int gy  = oy - 1 + yy;
                    const bool iny = (unsigned)gy < 128u;
                    float4 o0;
                    o0.x = (iny && (unsigned)(ox - 1 + x0 + 0) < 128u) ? fmaxf(a0[0] + bb, 0.f) : 0.f;
                    o0.y = (iny && (unsigned)(ox - 1 + x0 + 1) < 128u) ? fmaxf(a0[1] + bb, 0.f) : 0.f;
                    o0.z = (iny && (unsigned)(ox - 1 + x0 + 2) < 128u) ? fmaxf(a0[2] + bb, 0.f) : 0.f;
                    o0.w = (iny && (unsigned)(ox - 1 + x0 + 3) < 128u) ? fmaxf(a0[3] + bb, 0.f) : 0.f;
                    *(float4*)(&c1t[wvu * 648 + yy * 36 + x0]) = o0;
                }
            }
        }
        __syncthreads();   // c1t ready

        // ---- conv2: 1 pixel x 32 oc per thread over the 8 staged ci ----
        #pragma unroll 1
        for (int s = 0; s < 8; ++s) {
            float win[3][3];
            #pragma unroll
            for (int r = 0; r < 3; ++r) {
                const float* rp = &c1t[s * 648 + (y + r) * 36 + xb];
                const float2 u0 = *(const float2*)rp;
                const float2 u1 = *(const float2*)(rp + 2);
                win[r][0] = sel ? u0.y : u0.x;
                win[r][1] = sel ? u1.x : u0.y;
                win[r][2] = sel ? u1.y : u1.x;
            }
            const int cig = p * 8 + s;
            #pragma unroll
            for (int dy = 0; dy < 3; ++dy)
                #pragma unroll
                for (int dx = 0; dx < 3; ++dx) {
                    const float* wq = &Wk2[((dy * 3 + dx) * 32 + cig) * 32]; // uniform
                    const float av = win[dy][dx];
                    #pragma unroll
                    for (int oc = 0; oc < 32; ++oc)
                        acc[oc] = fmaf(av, wq[oc], acc[oc]);
                }
        }
    }

    // ---- epilogue: maxpool 4x4 within 16-lane group, bias+relu, NHWC ----
    float full[32];
    #pragma unroll
    for (int oc = 0; oc < 32; ++oc) {
        float m = acc[oc];
        m = fmaxf(m, __shfl_xor(m, 1, 64));
        m = fmaxf(m, __shfl_xor(m, 2, 64));
        m = fmaxf(m, __shfl_xor(m, 4, 64));
        m = fmaxf(m, __shfl_xor(m, 8, 64));
        full[oc] = fmaxf(m + b2[oc], 0.f);
    }
    if ((lane & 15) == 0) {                   // 4 writer lanes / wave
        const int py = ty * 4 + pyl;
        const int px = tx * 8 + pxl;
        float* op = &P1[((b * 32 + py) * 32 + px) * 32];
        #pragma unroll
        for (int q = 0; q < 8; ++q)
            *(float4*)(op + q * 4) = make_float4(full[q * 4], full[q * 4 + 1],
                                                 full[q * 4 + 2], full[q * 4 + 3]);
    }
}

// ---------------------------------------------------------------------------
// Fused weight repack: OIHW -> [k=(tap*CIN+ci)][oc] for w2..w6
// ---------------------------------------------------------------------------
__global__ void k_wrepack5(const float* __restrict__ w2, const float* __restrict__ w3,
                           const float* __restrict__ w4, const float* __restrict__ w5,
                           const float* __restrict__ w6,
                           float* __restrict__ Wk2, float* __restrict__ Wk3,
                           float* __restrict__ Wk4, float* __restrict__ Wk5,
                           float* __restrict__ Wk6)
{
    int idx = blockIdx.x * 256 + threadIdx.x;
    const float* w; float* Wk; int CIN, COUT;
    if (idx < 9216)         { w = w2; Wk = Wk2; CIN = 32;  COUT = 32; }
    else if (idx < 27648)   { idx -= 9216;   w = w3; Wk = Wk3; CIN = 32;  COUT = 64; }
    else if (idx < 64512)   { idx -= 27648;  w = w4; Wk = Wk4; CIN = 64;  COUT = 64; }
    else if (idx < 138240)  { idx -= 64512;  w = w5; Wk = Wk5; CIN = 64;  COUT = 128; }
    else if (idx < 285696)  { idx -= 138240; w = w6; Wk = Wk6; CIN = 128; COUT = 128; }
    else return;
    const int tap = idx / (CIN * COUT);
    const int rem = idx - tap * CIN * COUT;
    const int ci  = rem / COUT;
    const int oc  = rem - ci * COUT;
    Wk[idx] = w[(oc * CIN + ci) * 9 + tap];
}

// ---------------------------------------------------------------------------
// Implicit-GEMM conv3x3 (NHWC), register-prefetch pipelined:
// loads for chunk ch+1 issue right after the LDS-ready barrier, fly under the
// 1024-FMA compute block (VGPR-targeted loads don't drain at s_barrier).
// ---------------------------------------------------------------------------
template<int CIN, int COUT, int HW, int BM, int TM, int TN>
__global__ __launch_bounds__(256, 4)
void k_cgemm(const float* __restrict__ in, const float* __restrict__ Bk,
             const float* __restrict__ bias, float* __restrict__ out)
{
    constexpr int BN = 16 * TN;
    static_assert(BN == COUT, "one n-tile");
    constexpr int SA = (BM == 128) ? 140 : 68;
    constexpr int SB = (BN == 128) ? 140 : 68;
    constexpr int LOG = (HW == 32) ? 5 : 4;
    constexpr int NCH = (CIN * 9) / 32;
    constexpr int AF4 = (BM * 8) / 256;
    constexpr int BF4 = (BN * 8) / 256;

    __shared__ __align__(16) float As[32 * SA];
    __shared__ __align__(16) float Bs[32 * SB];

    const int t  = threadIdx.x;
    const int tm = t >> 4, tn = t & 15;
    const int m0 = blockIdx.x * BM;

    // fixed per-thread A-load coords
    int ay[AF4], ax[AF4], ab[AF4], ams[AF4], ac4[AF4];
    #pragma unroll
    for (int j = 0; j < AF4; ++j) {
        const int q    = t + 256 * j;
        const int mrow = q >> 3;
        ac4[j] = q & 7;
        const int m    = m0 + mrow;
        const int yx   = m & (HW * HW - 1);
        ab[j] = m >> (2 * LOG);
        ay[j] = yx >> LOG;
        ax[j] = yx & (HW - 1);
        ams[j] = mrow + ((mrow >> 5) << 2);
    }

    float acc[TM][TN];
    #pragma unroll
    for (int r = 0; r < TM; ++r)
        #pragma unroll
        for (int c = 0; c < TN; ++c) acc[r][c] = 0.f;

    float4 va[AF4], vb[BF4];
    auto loadA = [&](int ch) {
        const int kb  = ch * 32;
        const int tap = kb / CIN;
        const int c0  = kb - tap * CIN;
        const int dy  = tap / 3 - 1, dx = tap - (tap / 3) * 3 - 1;
        #pragma unroll
        for (int j = 0; j < AF4; ++j) {
            const int iy = ay[j] + dy, ix = ax[j] + dx;
            float4 v = make_float4(0.f, 0.f, 0.f, 0.f);
            if ((unsigned)iy < (unsigned)HW && (unsigned)ix < (unsigned)HW)
                v = *(const float4*)(in + ((ab[j] * HW + iy) * HW + ix) * CIN + c0 + ac4[j] * 4);
            va[j] = v;
        }
    };
    auto loadB = [&](int ch) {
        const int kb = ch * 32;
        #pragma unroll
        for (int j = 0; j < BF4; ++j) {
            const int q  = t + 256 * j;
            const int kk = q / (BN / 4), n4 = q - kk * (BN / 4);
            vb[j] = *(const float4*)(Bk + (kb + kk) * COUT + n4 * 4);
        }
    };

    loadA(0); loadB(0);

    #pragma unroll 1
    for (int ch = 0; ch < NCH; ++ch) {
        if (ch) __syncthreads();
        #pragma unroll
        for (int j = 0; j < AF4; ++j) {
            As[(ac4[j] * 4 + 0) * SA + ams[j]] = va[j].x;
            As[(ac4[j] * 4 + 1) * SA + ams[j]] = va[j].y;
            As[(ac4[j] * 4 + 2) * SA + ams[j]] = va[j].z;
            As[(ac4[j] * 4 + 3) * SA + ams[j]] = va[j].w;
        }
        #pragma unroll
        for (int j = 0; j < BF4; ++j) {
            const int q  = t + 256 * j;
            const int kk = q / (BN / 4), n4 = q - kk * (BN / 4);
            *(float4*)(&Bs[kk * SB + n4 * 4 + ((n4 >> 3) << 2)]) = vb[j];
        }
        __syncthreads();
        if (ch + 1 < NCH) { loadA(ch + 1); loadB(ch + 1); }

        #pragma unroll 2
        for (int kk = 0; kk < 32; ++kk) {
            const float* ap = &As[kk * SA + tm * TM + (((tm * TM) >> 5) << 2)];
            const float* bp = &Bs[kk * SB + tn * TN + (((tn * TN) >> 5) << 2)];
            float a[TM], bb[TN];
            #pragma unroll
            for (int j = 0; j < TM; j += 4) {
                const float4 v = *(const float4*)(ap + j);
                a[j] = v.x; a[j + 1] = v.y; a[j + 2] = v.z; a[j + 3] = v.w;
            }
            #pragma unroll
            for (int j = 0; j < TN; j += 4) {
                const float4 v = *(const float4*)(bp + j);
                bb[j] = v.x; bb[j + 1] = v.y; bb[j + 2] = v.z; bb[j + 3] = v.w;
            }
            #pragma unroll
            for (int r = 0; r < TM; ++r)
                #pragma unroll
                for (int c = 0; c < TN; ++c)
                    acc[r][c] = fmaf(a[r], bb[c], acc[r][c]);
        }
    }

    #pragma unroll
    for (int r = 0; r < TM; ++r) {
        const int m = m0 + tm * TM + r;
        float* op = out + m * COUT + tn * TN;
        #pragma unroll
        for (int c = 0; c < TN; c += 4) {
            float4 v;
            v.x = fmaxf(acc[r][c + 0] + bias[tn * TN + c + 0], 0.f);
            v.y = fmaxf(acc[r][c + 1] + bias[tn * TN + c + 1], 0.f);
            v.z = fmaxf(acc[r][c + 2] + bias[tn * TN + c + 2], 0.f);
            v.w = fmaxf(acc[r][c + 3] + bias[tn * TN + c + 3], 0.f);
            *(float4*)(op + c) = v;
        }
    }
}

// ---------------------------------------------------------------------------
// 2x2 maxpool, NHWC [128][32][32][64] -> [128][16][16][64]
// ---------------------------------------------------------------------------
__global__ __launch_bounds__(256)
void k_pool2(const float* __restrict__ in, float* __restrict__ out)
{
    const int g = blockIdx.x * 256 + threadIdx.x;
    const int c4 = g & 15, xo = (g >> 4) & 15, yo = (g >> 8) & 15, b = g >> 12;
    const float* p = in + ((b * 32 + yo * 2) * 32 + xo * 2) * 64 + c4 * 4;
    const float4 v0 = *(const float4*)(p);
    const float4 v1 = *(const float4*)(p + 64);
    const float4 v2 = *(const float4*)(p + 2048);
    const float4 v3 = *(const float4*)(p + 2112);
    float4 o;
    o.x = fmaxf(fmaxf(v0.x, v1.x), fmaxf(v2.x, v3.x));
    o.y = fmaxf(fmaxf(v0.y, v1.y), fmaxf(v2.y, v3.y));
    o.z = fmaxf(fmaxf(v0.z, v1.z), fmaxf(v2.z, v3.z));
    o.w = fmaxf(fmaxf(v0.w, v1.w), fmaxf(v2.w, v3.w));
    *(float4*)(out + g * 4) = o;
}

// ---------------------------------------------------------------------------
// Split-K FC partial (register-prefetch pipelined, float4 staging):
// A[128 x K] @ B[K x 512] -> part[ky][128][512]
// ---------------------------------------------------------------------------
template<int LDA, int KCHUNK, int TN, bool PERM>
__global__ __launch_bounds__(256, 2)
void k_fc_partial(const float* __restrict__ A, const float* __restrict__ Bw,
                  float* __restrict__ part)
{
    constexpr int BN = 16 * TN;
    constexpr int SA = 140;
    constexpr int SB = (BN == 128) ? 140 : 68;
    constexpr int NKS = KCHUNK / 32;
    constexpr int BF4 = BN / 32;
    __shared__ __align__(16) float As[32 * SA];
    __shared__ __align__(16) float Bs[32 * SB];
    const int t  = threadIdx.x;
    const int tm = t >> 4, tn = t & 15;
    const int n0 = blockIdx.x * BN;
    const int k0 = blockIdx.y * KCHUNK;

    float acc[8][TN];
    #pragma unroll
    for (int r = 0; r < 8; ++r)
        #pragma unroll
        for (int c = 0; c < TN; ++c) acc[r][c] = 0.f;

    float4 va[4], vb[BF4];
    auto loadA = [&](int ks) {
        const int kb = k0 + ks * 32;
        #pragma unroll
        for (int j = 0; j < 4; ++j) {
            const int idx = t + 256 * j;
            const int m = idx >> 3, k4 = idx & 7;
            va[j] = *(const float4*)(A + m * LDA + kb + k4 * 4);
        }
    };
    auto loadB = [&](int ks) {
        const int kb = k0 + ks * 32;
        #pragma unroll
        for (int j = 0; j < BF4; ++j) {
            const int q  = t + 256 * j;
            const int kk = q / (BN / 4), n4 = q - kk * (BN / 4);
            const int krow = kb + kk;
            const int kref = PERM ? ((krow & 127) * 256 + (krow >> 7)) : krow;
            vb[j] = *(const float4*)(Bw + kref * 512 + n0 + n4 * 4);
        }
    };

    loadA(0); loadB(0);

    #pragma unroll 1
    for (int ks = 0; ks < NKS; ++ks) {
        if (ks) __syncthreads();
        #pragma unroll
        for (int j = 0; j < 4; ++j) {
            const int idx = t + 256 * j;
            const int m = idx >> 3, k4 = idx & 7;
            const int ms = m + ((m >> 5) << 2);
            As[(k4 * 4 + 0) * SA + ms] = va[j].x;
            As[(k4 * 4 + 1) * SA + ms] = va[j].y;
            As[(k4 * 4 + 2) * SA + ms] = va[j].z;
            As[(k4 * 4 + 3) * SA + ms] = va[j].w;
        }
        #pragma unroll
        for (int j = 0; j < BF4; ++j) {
            const int q  = t + 256 * j;
            const int kk = q / (BN / 4), n4 = q - kk * (BN / 4);
            *(float4*)(&Bs[kk * SB + n4 * 4 + ((n4 >> 3) << 2)]) = vb[j];
        }
        __syncthreads();
        if (ks + 1 < NKS) { loadA(ks + 1); loadB(ks + 1); }

        #pragma unroll 2
        for (int kk = 0; kk < 32; ++kk) {
            const float* ap = &As[kk * SA + tm * 8 + ((tm >> 2) << 2)];
            const float* bp = &Bs[kk * SB + tn * TN + (((tn * TN) >> 5) << 2)];
            float a[8], bb[TN];
            #pragma unroll
            for (int q = 0; q < 8; q += 4) {
                const float4 v = *(const float4*)(ap + q);
                a[q] = v.x; a[q + 1] = v.y; a[q + 2] = v.z; a[q + 3] = v.w;
            }
            #pragma unroll
            for (int q = 0; q < TN; q += 4) {
                const float4 v = *(const float4*)(bp + q);
                bb[q] = v.x; bb[q + 1] = v.y; bb[q + 2] = v.z; bb[q + 3] = v.w;
            }
            #pragma unroll
            for (int r = 0; r < 8; ++r)
                #pragma unroll
                for (int c = 0; c < TN; ++c)
                    acc[r][c] = fmaf(a[r], bb[c], acc[r][c]);
        }
    }

    const long pb = (long)blockIdx.y * 65536;
    #pragma unroll
    for (int r = 0; r < 8; ++r)
        #pragma unroll
        for (int c = 0; c < TN; ++c)
            part[pb + (tm * 8 + r) * 512 + n0 + tn * TN + c] = acc[r][c];
}

template<int NS>
__global__ __launch_bounds__(256)
void k_fc_reduce(const float* __restrict__ part, const float* __restrict__ bias,
                 float* __restrict__ H)
{
    const int f = (blockIdx.x * 256 + threadIdx.x) * 4;
    const int m = f >> 9, n = f & 511;
    float s0 = 0.f, s1 = 0.f, s2 = 0.f, s3 = 0.f;
    #pragma unroll 4
    for (int q = 0; q < NS; ++q) {
        const float* p = &part[(q * 128 + m) * 512 + n];
        s0 += p[0]; s1 += p[1]; s2 += p[2]; s3 += p[3];
    }
    H[f]     = fmaxf(s0 + bias[n],     0.f);
    H[f + 1] = fmaxf(s1 + bias[n + 1], 0.f);
    H[f + 2] = fmaxf(s2 + bias[n + 2], 0.f);
    H[f + 3] = fmaxf(s3 + bias[n + 3], 0.f);
}

// ---------------------------------------------------------------------------
// Final: FC3 + sampling + patch gather
// ---------------------------------------------------------------------------
__device__ __forceinline__ float softplusf(float x) {
    return (x > 20.f) ? x : log1pf(expf(x));
}
__device__ __forceinline__ float sigmoidf_(float x) {
    return 1.f / (1.f + expf(-x));
}

__global__ __launch_bounds__(256)
void k_final(const float* __restrict__ H2, const float* __restrict__ wl3,
             const float* __restrict__ bl3, const float* __restrict__ noise,
             const float* __restrict__ img, float* __restrict__ outp)
{
    __shared__ float h2[512];
    __shared__ float red[144];
    __shared__ float prep[36];
    __shared__ int ptsh[12], ptsw[12];
    const int b = blockIdx.x, t = threadIdx.x;

    h2[t]       = H2[b * 512 + t];
    h2[t + 256] = H2[b * 512 + 256 + t];
    __syncthreads();

    if (t < 144) {
        const int n = t >> 2, q = t & 3;
        float s = 0.f;
        for (int k = q * 128; k < q * 128 + 128; ++k)
            s = fmaf(h2[k], wl3[k * 36 + n], s);
        red[t] = s;
    }
    __syncthreads();
    if (t < 36)
        prep[t] = red[t * 4] + red[t * 4 + 1] + red[t * 4 + 2] + red[t * 4 + 3] + bl3[t];
    __syncthreads();

    if (t < 12) {
        const float m0 = prep[t * 3], m1 = prep[t * 3 + 1], sv = prep[t * 3 + 2];
        const float sig = softplusf(sv + 2.0f) * 128.f + 1e-7f;
        const float n0 = noise[(b * 12 + t) * 2], n1 = noise[(b * 12 + t) * 2 + 1];
        const float sa0 = m0 + sig * n0;
        const float sa1 = m1 + sig * n1;
        int p0 = (int)rintf(sigmoidf_(sa0) * 111.f);
        int p1 = (int)rintf(sigmoidf_(sa1) * 111.f);
        p0 = min(max(p0, 0), 111);
        p1 = min(max(p1, 0), 111);
        const int RM = 1179648;
        outp[RM        + (b * 12 + t) * 2 + 0] = m0;
        outp[RM        + (b * 12 + t) * 2 + 1] = m1;
        outp[RM + 3072 + (b * 12 + t) * 2 + 0] = sig;
        outp[RM + 3072 + (b * 12 + t) * 2 + 1] = sig;
        outp[RM + 6144 + (b * 12 + t) * 2 + 0] = sa0;
        outp[RM + 6144 + (b * 12 + t) * 2 + 1] = sa1;
        ptsh[t] = p0;
        ptsw[t] = p1;
    }
    __syncthreads();

    for (int i = t; i < 9216; i += 256) {
        const int g  = i / 768, r = i - g * 768;
        const int c  = r >> 8, r2 = r & 255;
        const int y  = r2 >> 4, x = r2 & 15;
        outp[b * 9216 + i] = img[((b * 3 + c) * 128 + ptsh[g] + y) * 128 + (ptsw[g] + x)];
    }
}

// ---------------------------------------------------------------------------
extern "C" void kernel_launch(void* const* d_in, const int* in_sizes, int n_in,
                              void* d_out, int out_size, void* d_ws, size_t ws_size,
                              hipStream_t stream)
{
    const float* img  = (const float*)d_in[0];
    const float* nois = (const float*)d_in[1];
    const float* w1 = (const float*)d_in[2];  const float* b1 = (const float*)d_in[3];
    const float* w2 = (const float*)d_in[4];  const float* b2 = (const float*)d_in[5];
    const float* w3 = (const float*)d_in[6];  const float* b3 = (const float*)d_in[7];
    const float* w4 = (const float*)d_in[8];  const float* b4 = (const float*)d_in[9];
    const float* w5 = (const float*)d_in[10]; const float* b5 = (const float*)d_in[11];
    const float* w6 = (const float*)d_in[12]; const float* b6 = (const float*)d_in[13];
    const float* wl1 = (const float*)d_in[14]; const float* bl1 = (const float*)d_in[15];
    const float* wl2 = (const float*)d_in[16]; const float* bl2 = (const float*)d_in[17];
    const float* wl3 = (const float*)d_in[18]; const float* bl3 = (const float*)d_in[19];
    float* out = (float*)d_out;
    float* ws  = (float*)d_ws;

    float* P1   = ws;                    // [128][32][32][32] NHWC
    float* P2   = ws;                    // [128][16][16][64] NHWC (aliases P1)
    float* A3   = ws + 4194304;          // [128][32][32][64] NHWC
    float* A4f  = ws + 12582912;         // [128][32][32][64] NHWC
    float* A5   = ws + 12582912;         // [128][16][16][128] NHWC (aliases A4f)
    float* A6   = ws + 16777216;         // [128][16][16][128] NHWC
    float* FP1  = ws + 20971520;         // [64][128][512]
    float* H1   = ws + 25165824;         // [128][512]
    float* FP2  = ws + 25231360;         // [16][128][512]
    float* H2   = ws + 26279936;         // [128][512]
    float* Wk3  = ws + 26345472;         // [288][64]
    float* Wk4  = ws + 26363904;         // [576][64]
    float* Wk5  = ws + 26400768;         // [576][128]
    float* Wk6  = ws + 26474496;         // [1152][128]
    float* Wk2  = ws + 26621952;         // [288][32]

    hipLaunchKernelGGL(k_wrepack5, dim3(1116), dim3(256), 0, stream,
                       w2, w3, w4, w5, w6, Wk2, Wk3, Wk4, Wk5, Wk6);

    hipLaunchKernelGGL(k_conv12, dim3(32, 128), dim3(512), 0, stream,
                       img, w1, b1, Wk2, b2, P1);
    hipLaunchKernelGGL((k_cgemm<32, 64, 32, 128, 8, 4>), dim3(1024), dim3(256), 0, stream,
                       P1, Wk3, b3, A3);
    hipLaunchKernelGGL((k_cgemm<64, 64, 32, 128, 8, 4>), dim3(1024), dim3(256), 0, stream,
                       A3, Wk4, b4, A4f);
    hipLaunchKernelGGL(k_pool2, dim3(2048), dim3(256), 0, stream, A4f, P2);
    hipLaunchKernelGGL((k_cgemm<64, 128, 16, 64, 4, 8>), dim3(512), dim3(256), 0, stream,
                       P2, Wk5, b5, A5);
    hipLaunchKernelGGL((k_cgemm<128, 128, 16, 64, 4, 8>), dim3(512), dim3(256), 0, stream,
                       A5, Wk6, b6, A6);
    hipLaunchKernelGGL((k_fc_partial<32768, 512, 4, true>), dim3(8, 64), dim3(256), 0, stream,
                       A6, wl1, FP1);
    hipLaunchKernelGGL(k_fc_reduce<64>, dim3(64), dim3(256), 0, stream, FP1, bl1, H1);
    hipLaunchKernelGGL((k_fc_partial<512, 32, 4, false>), dim3(8, 16), dim3(256), 0, stream,
                       H1, wl2, FP2);
    hipLaunchKernelGGL(k_fc_reduce<16>, dim3(64), dim3(256), 0, stream, FP2, bl2, H2);
    hipLaunchKernelGGL(k_final, dim3(128), dim3(256), 0, stream,
                       H2, wl3, bl3, nois, img, out);
}

// Round 8
// 887.584 us; speedup vs baseline: 1.5764x; 1.5764x over previous
//
#include <hip/hip_runtime.h>
#include <math.h>

typedef _Float16 __attribute__((ext_vector_type(8))) half8_t;
typedef _Float16 __attribute__((ext_vector_type(4))) half4_t;
typedef float    __attribute__((ext_vector_type(4))) float4_t;

// ---------------------------------------------------------------------------
// Kernel 1: fused conv1+relu+conv2+relu+maxpool4  (R5 structure, 452us known)
// Output: dual fp16 planes P1h/P1l, NHWC [128][32][32][32].
// ---------------------------------------------------------------------------
__global__ __launch_bounds__(256, 4)
void k_conv12(const float* __restrict__ img, const float* __restrict__ w1,
              const float* __restrict__ b1, const float* __restrict__ Wk2,
              const float* __restrict__ b2,
              _Float16* __restrict__ P1h, _Float16* __restrict__ P1l)
{
    __shared__ float simg[3 * 20 * 36 + 4];
    __shared__ float c1t[8 * 18 * 36];

    const int t  = threadIdx.x;
    const int bt = blockIdx.x;
    const int b  = blockIdx.y;
    const int ty = bt >> 2, tx = bt & 3;
    const int oy = ty * 16, ox = tx * 32;

    for (int i = t; i < 2160; i += 256) {
        const int ci = i / 720, r = i - ci * 720;
        const int yy = r / 36, xx = r - yy * 36;
        const int gy = oy - 2 + yy, gx = ox - 2 + xx;
        float v = 0.f;
        if ((unsigned)gy < 128u && (unsigned)gx < 128u)
            v = img[((b * 3 + ci) * 128 + gy) * 128 + gx];
        simg[i] = v;
    }

    const int wvu  = __builtin_amdgcn_readfirstlane(t >> 6);
    const int lane = t & 63;
    const int y    = t >> 4;
    const int x    = (t & 15) * 2;

    float acc0[32], acc1[32];
    #pragma unroll
    for (int j = 0; j < 32; ++j) { acc0[j] = 0.f; acc1[j] = 0.f; }

    #pragma unroll 1
    for (int p = 0; p < 4; ++p) {
        __syncthreads();

        {
            const int chb = p * 8 + wvu * 2;
            float w1r[2][27];
            #pragma unroll
            for (int j = 0; j < 2; ++j)
                #pragma unroll
                for (int q = 0; q < 27; ++q)
                    w1r[j][q] = w1[(chb + j) * 27 + q];
            const float bb0 = b1[chb], bb1 = b1[chb + 1];

            #pragma unroll 1
            for (int it = 0; it < 3; ++it) {
                const int s = lane + it * 64;
                if (s < 162) {
                    const int yy = s / 9;
                    const int x0 = (s - yy * 9) * 4;
                    float a0[4] = {0.f, 0.f, 0.f, 0.f};
                    float a1[4] = {0.f, 0.f, 0.f, 0.f};
                    #pragma unroll
                    for (int ci = 0; ci < 3; ++ci)
                        #pragma unroll
                        for (int dy = 0; dy < 3; ++dy) {
                            const float* rp = &simg[ci * 720 + (yy + dy) * 36 + x0];
                            const float4 v4 = *(const float4*)rp;
                            const float2 v2 = *(const float2*)(rp + 4);
                            const float in6[6] = {v4.x, v4.y, v4.z, v4.w, v2.x, v2.y};
                            const int wb = ci * 9 + dy * 3;
                            #pragma unroll
                            for (int c = 0; c < 4; ++c) {
                                a0[c] = fmaf(w1r[0][wb],     in6[c],     a0[c]);
                                a0[c] = fmaf(w1r[0][wb + 1], in6[c + 1], a0[c]);
                                a0[c] = fmaf(w1r[0][wb + 2], in6[c + 2], a0[c]);
                                a1[c] = fmaf(w1r[1][wb],     in6[c],     a1[c]);
                                a1[c] = fmaf(w1r[1][wb + 1], in6[c + 1], a1[c]);
                                a1[c] = fmaf(w1r[1][wb + 2], in6[c + 2], a1[c]);
                            }
                        }
                    const int gy  = oy - 1 + yy;
                    const bool iny = (unsigned)gy < 128u;
                    const bool i0 = iny && (unsigned)(ox - 1 + x0 + 0) < 128u;
                    const bool i1 = iny && (unsigned)(ox - 1 + x0 + 1) < 128u;
                    const bool i2 = iny && (unsigned)(ox - 1 + x0 + 2) < 128u;
                    const bool i3 = iny && (unsigned)(ox - 1 + x0 + 3) < 128u;
                    float4 o0, o1;
                    o0.x = i0 ? fmaxf(a0[0] + bb0, 0.f) : 0.f;
                    o0.y = i1 ? fmaxf(a0[1] + bb0, 0.f) : 0.f;
                    o0.z = i2 ? fmaxf(a0[2] + bb0, 0.f) : 0.f;
                    o0.w = i3 ? fmaxf(a0[3] + bb0, 0.f) : 0.f;
                    o1.x = i0 ? fmaxf(a1[0] + bb1, 0.f) : 0.f;
                    o1.y = i1 ? fmaxf(a1[1] + bb1, 0.f) : 0.f;
                    o1.z = i2 ? fmaxf(a1[2] + bb1, 0.f) : 0.f;
                    o1.w = i3 ? fmaxf(a1[3] + bb1, 0.f) : 0.f;
                    *(float4*)(&c1t[(wvu * 2 + 0) * 648 + yy * 36 + x0]) = o0;
                    *(float4*)(&c1t[(wvu * 2 + 1) * 648 + yy * 36 + x0]) = o1;
                }
            }
        }
        __syncthreads();

        #pragma unroll 1
        for (int s = 0; s < 8; ++s) {
            float win[3][4];
            #pragma unroll
            for (int r = 0; r < 3; ++r) {
                const float* rp = &c1t[s * 648 + (y + r) * 36 + x];
                const float2 u0 = *(const float2*)rp;
                const float2 u1 = *(const float2*)(rp + 2);
                win[r][0] = u0.x; win[r][1] = u0.y;
                win[r][2] = u1.x; win[r][3] = u1.y;
            }
            const int cig = p * 8 + s;
            #pragma unroll
            for (int dy = 0; dy < 3; ++dy)
                #pragma unroll
                for (int dx = 0; dx < 3; ++dx) {
                    const float* wq = &Wk2[((dy * 3 + dx) * 32 + cig) * 32];
                    const float a0v = win[dy][dx];
                    const float a1v = win[dy][dx + 1];
                    #pragma unroll
                    for (int oc = 0; oc < 32; ++oc) {
                        const float wv = wq[oc];
                        acc0[oc] = fmaf(a0v, wv, acc0[oc]);
                        acc1[oc] = fmaf(a1v, wv, acc1[oc]);
                    }
                }
        }
    }

    float full[32];
    #pragma unroll
    for (int oc = 0; oc < 32; ++oc) {
        float m = fmaxf(acc0[oc], acc1[oc]);
        m = fmaxf(m, __shfl_xor(m, 1, 64));
        m = fmaxf(m, __shfl_xor(m, 16, 64));
        m = fmaxf(m, __shfl_xor(m, 32, 64));
        full[oc] = fmaxf(m + b2[oc], 0.f);
    }
    if ((lane & 1) == 0 && (lane >> 4) == 0) {
        const int py = ty * 4 + wvu;
        const int px = tx * 8 + (lane >> 1);
        const int base = ((b * 32 + py) * 32 + px) * 32;
        #pragma unroll
        for (int q = 0; q < 8; ++q) {
            half4_t h, l;
            #pragma unroll
            for (int e = 0; e < 4; ++e) {
                const float v = full[q * 4 + e];
                const _Float16 hh = (_Float16)v;
                h[e] = hh;
                l[e] = (_Float16)(v - (float)hh);
            }
            *(half4_t*)(&P1h[base + q * 4]) = h;
            *(half4_t*)(&P1l[base + q * 4]) = l;
        }
    }
}

// ---------------------------------------------------------------------------
// Weight repack: Wk2 (fp32, conv12) + fp16 hi/lo MFMA-fragment packs for w3..w6
// Frag order: Bh[((c*NT + ntg)*64 + lane)*8 + j], element B[k][n]:
//   n = ntg*16 + (lane&15), k = c*32 + (lane>>4)*8 + j.
// ---------------------------------------------------------------------------
__global__ void k_wrepackm(const float* __restrict__ w2, const float* __restrict__ w3,
                           const float* __restrict__ w4, const float* __restrict__ w5,
                           const float* __restrict__ w6, float* __restrict__ Wk2,
                           _Float16* __restrict__ Bh, _Float16* __restrict__ Bl)
{
    int idx = blockIdx.x * 256 + threadIdx.x;
    if (idx < 9216) {
        const int tap = idx / 1024, rem = idx - tap * 1024;
        const int ci = rem / 32, oc = rem & 31;
        Wk2[idx] = w2[(oc * 32 + ci) * 9 + tap];
        return;
    }
    idx -= 9216;
    const float* w; int CIN, COUT, off;
    if (idx < 18432)       { w = w3; CIN = 32;  COUT = 64;  off = 0; }
    else if (idx < 55296)  { idx -= 18432;  w = w4; CIN = 64;  COUT = 64;  off = 18432; }
    else if (idx < 129024) { idx -= 55296;  w = w5; CIN = 64;  COUT = 128; off = 55296; }
    else if (idx < 276480) { idx -= 129024; w = w6; CIN = 128; COUT = 128; off = 129024; }
    else return;
    const int NT  = COUT / 16;
    const int c   = idx / (NT * 512);
    const int r   = idx - c * NT * 512;
    const int ntg = r >> 9;
    const int rr  = r & 511;
    const int lane = rr >> 3, j = rr & 7;
    const int k   = c * 32 + (lane >> 4) * 8 + j;
    const int tap = k / CIN, ci = k - tap * CIN;
    const int oc  = ntg * 16 + (lane & 15);
    const float v = w[(oc * CIN + ci) * 9 + tap];
    const _Float16 h = (_Float16)v;
    Bh[off + idx] = h;
    Bl[off + idx] = (_Float16)(v - (float)h);
}

// ---------------------------------------------------------------------------
// MFMA implicit-GEMM conv3x3, fp16x4 split (fp32-accurate).
// BM=128, BN=64 per block; 4 waves, wave = 2 m-tiles x 4 n-tiles.
// A: dual fp16 NHWC planes -> LDS m-major [128][PS=40] halves (b128 frags).
// B: prepacked fragment order, read straight from global (coalesced 16B/lane).
// acc += Ah*Bh + Al*Bh + Ah*Bl + Al*Bl  (split terms make it fp32-class).
// ---------------------------------------------------------------------------
template<int CIN, int COUT, int HW, bool OUTF32>
__global__ __launch_bounds__(256, 2)
void k_mgemm(const _Float16* __restrict__ inh, const _Float16* __restrict__ inl,
             const _Float16* __restrict__ Bh, const _Float16* __restrict__ Bl,
             const float* __restrict__ bias,
             _Float16* __restrict__ outh, _Float16* __restrict__ outl,
             float* __restrict__ outf)
{
    constexpr int NCH = CIN * 9 / 32;
    constexpr int NT  = COUT / 16;
    constexpr int LOG = (HW == 32) ? 5 : 4;
    constexpr int PS  = 40;
    __shared__ _Float16 Ash[128 * PS];
    __shared__ _Float16 Asl[128 * PS];

    const int t    = threadIdx.x;
    const int wv   = t >> 6;
    const int lane = t & 63;
    const int m0   = blockIdx.x * 128;
    const int nb   = blockIdx.y;

    int sm[2], sg[2], sb[2], sy[2], sx[2];
    #pragma unroll
    for (int j = 0; j < 2; ++j) {
        const int q = t + 256 * j;
        sm[j] = q >> 2;
        sg[j] = q & 3;
        const int m  = m0 + sm[j];
        const int yx = m & (HW * HW - 1);
        sb[j] = m >> (2 * LOG);
        sy[j] = yx >> LOG;
        sx[j] = yx & (HW - 1);
    }

    const int mt0 = wv * 2;
    const int fr  = lane >> 4;
    const int ml  = lane & 15;

    float4_t acc[2][4];
    #pragma unroll
    for (int mt = 0; mt < 2; ++mt)
        #pragma unroll
        for (int tn = 0; tn < 4; ++tn)
            acc[mt][tn] = (float4_t){0.f, 0.f, 0.f, 0.f};

    #pragma unroll 1
    for (int ch = 0; ch < NCH; ++ch) {
        const int kb  = ch * 32;
        const int tap = kb / CIN;
        const int c0  = kb - tap * CIN;
        const int dy  = tap / 3 - 1, dx = tap - (tap / 3) * 3 - 1;

        if (ch) __syncthreads();
        #pragma unroll
        for (int j = 0; j < 2; ++j) {
            const int iy = sy[j] + dy, ix = sx[j] + dx;
            half8_t vh = {0, 0, 0, 0, 0, 0, 0, 0};
            half8_t vl = {0, 0, 0, 0, 0, 0, 0, 0};
            if ((unsigned)iy < (unsigned)HW && (unsigned)ix < (unsigned)HW) {
                const int o = ((sb[j] * HW + iy) * HW + ix) * CIN + c0 + sg[j] * 8;
                vh = *(const half8_t*)(inh + o);
                vl = *(const half8_t*)(inl + o);
            }
            *(half8_t*)(&Ash[sm[j] * PS + sg[j] * 8]) = vh;
            *(half8_t*)(&Asl[sm[j] * PS + sg[j] * 8]) = vl;
        }
        __syncthreads();

        half8_t ah[2], al[2];
        #pragma unroll
        for (int mt = 0; mt < 2; ++mt) {
            const int mr = (mt0 + mt) * 16 + ml;
            ah[mt] = *(const half8_t*)(&Ash[mr * PS + fr * 8]);
            al[mt] = *(const half8_t*)(&Asl[mr * PS + fr * 8]);
        }
        half8_t bh[4], bl[4];
        #pragma unroll
        for (int tn = 0; tn < 4; ++tn) {
            const int bo = ((ch * NT + nb * 4 + tn) * 64 + lane) * 8;
            bh[tn] = *(const half8_t*)(Bh + bo);
            bl[tn] = *(const half8_t*)(Bl + bo);
        }
        #pragma unroll
        for (int tn = 0; tn < 4; ++tn)
            #pragma unroll
            for (int mt = 0; mt < 2; ++mt)
                acc[mt][tn] = __builtin_amdgcn_mfma_f32_16x16x32_f16(ah[mt], bh[tn], acc[mt][tn], 0, 0, 0);
        #pragma unroll
        for (int tn = 0; tn < 4; ++tn)
            #pragma unroll
            for (int mt = 0; mt < 2; ++mt)
                acc[mt][tn] = __builtin_amdgcn_mfma_f32_16x16x32_f16(al[mt], bh[tn], acc[mt][tn], 0, 0, 0);
        #pragma unroll
        for (int tn = 0; tn < 4; ++tn)
            #pragma unroll
            for (int mt = 0; mt < 2; ++mt)
                acc[mt][tn] = __builtin_amdgcn_mfma_f32_16x16x32_f16(ah[mt], bl[tn], acc[mt][tn], 0, 0, 0);
        #pragma unroll
        for (int tn = 0; tn < 4; ++tn)
            #pragma unroll
            for (int mt = 0; mt < 2; ++mt)
                acc[mt][tn] = __builtin_amdgcn_mfma_f32_16x16x32_f16(al[mt], bl[tn], acc[mt][tn], 0, 0, 0);
    }

    // epilogue: C/D frag col=lane&15, row=(lane>>4)*4+reg  [guide m89/m91]
    #pragma unroll
    for (int mt = 0; mt < 2; ++mt)
        #pragma unroll
        for (int tn = 0; tn < 4; ++tn) {
            const int oc = nb * 64 + tn * 16 + ml;
            const float bv = bias[oc];
            #pragma unroll
            for (int r = 0; r < 4; ++r) {
                const int m = m0 + (mt0 + mt) * 16 + fr * 4 + r;
                const float v = fmaxf(acc[mt][tn][r] + bv, 0.f);
                if (OUTF32) {
                    outf[m * COUT + oc] = v;
                } else {
                    const _Float16 h = (_Float16)v;
                    outh[m * COUT + oc] = h;
                    outl[m * COUT + oc] = (_Float16)(v - (float)h);
                }
            }
        }
}

// ---------------------------------------------------------------------------
// 2x2 maxpool on dual fp16 planes, NHWC [128][32][32][64] -> [128][16][16][64]
// ---------------------------------------------------------------------------
__global__ __launch_bounds__(256)
void k_pool2h(const _Float16* __restrict__ inh, const _Float16* __restrict__ inl,
              _Float16* __restrict__ outh, _Float16* __restrict__ outl)
{
    const int g = blockIdx.x * 256 + threadIdx.x;
    const int c4 = g & 15, xo = (g >> 4) & 15, yo = (g >> 8) & 15, b = g >> 12;
    const int base = ((b * 32 + yo * 2) * 32 + xo * 2) * 64 + c4 * 4;
    const int offs[4] = {0, 64, 2048, 2112};
    float mx[4] = {-1e30f, -1e30f, -1e30f, -1e30f};
    #pragma unroll
    for (int cnd = 0; cnd < 4; ++cnd) {
        const half4_t h = *(const half4_t*)(inh + base + offs[cnd]);
        const half4_t l = *(const half4_t*)(inl + base + offs[cnd]);
        #pragma unroll
        for (int e = 0; e < 4; ++e)
            mx[e] = fmaxf(mx[e], (float)h[e] + (float)l[e]);
    }
    half4_t oh, ol;
    #pragma unroll
    for (int e = 0; e < 4; ++e) {
        const _Float16 h = (_Float16)mx[e];
        oh[e] = h;
        ol[e] = (_Float16)(mx[e] - (float)h);
    }
    const int ob = ((b * 16 + yo) * 16 + xo) * 64 + c4 * 4;
    *(half4_t*)(outh + ob) = oh;
    *(half4_t*)(outl + ob) = ol;
}

// ---------------------------------------------------------------------------
// Split-K FC partial (fp32): A[128 x K] @ B[K x 512] -> part[ky][128][512]
// ---------------------------------------------------------------------------
template<int LDA, int KCHUNK, int TN, bool PERM>
__global__ __launch_bounds__(256, 2)
void k_fc_partial(const float* __restrict__ A, const float* __restrict__ Bw,
                  float* __restrict__ part)
{
    constexpr int BN = 16 * TN;
    constexpr int SA = 140;
    constexpr int SB = (BN == 128) ? 140 : 68;
    __shared__ __align__(16) float As[32 * SA];
    __shared__ __align__(16) float Bs[32 * SB];
    const int t  = threadIdx.x;
    const int tm = t >> 4, tn = t & 15;
    const int n0 = blockIdx.x * BN;
    const int k0 = blockIdx.y * KCHUNK;

    float acc[8][TN];
    #pragma unroll
    for (int r = 0; r < 8; ++r)
        #pragma unroll
        for (int c = 0; c < TN; ++c) acc[r][c] = 0.f;

    #pragma unroll 1
    for (int ks = 0; ks < KCHUNK / 32; ++ks) {
        if (ks) __syncthreads();
        const int kb = k0 + ks * 32;
        for (int i = t; i < 4096; i += 256) {
            const int m = i >> 5, kk = i & 31;
            As[kk * SA + m + ((m >> 5) << 2)] = A[m * LDA + kb + kk];
        }
        for (int i = t; i < 32 * BN; i += 256) {
            const int kk = i / BN, n = i - kk * BN;
            const int krow = kb + kk;
            const int kref = PERM ? ((krow & 127) * 256 + (krow >> 7)) : krow;
            Bs[kk * SB + n + ((n >> 5) << 2)] = Bw[kref * 512 + n0 + n];
        }
        __syncthreads();
        #pragma unroll 2
        for (int kk = 0; kk < 32; ++kk) {
            const float* ap = &As[kk * SA + tm * 8 + ((tm >> 2) << 2)];
            const float* bp = &Bs[kk * SB + tn * TN + (((tn * TN) >> 5) << 2)];
            float a[8], bb[TN];
            #pragma unroll
            for (int q = 0; q < 8; q += 4) {
                const float4 v = *(const float4*)(ap + q);
                a[q] = v.x; a[q + 1] = v.y; a[q + 2] = v.z; a[q + 3] = v.w;
            }
            #pragma unroll
            for (int q = 0; q < TN; q += 4) {
                const float4 v = *(const float4*)(bp + q);
                bb[q] = v.x; bb[q + 1] = v.y; bb[q + 2] = v.z; bb[q + 3] = v.w;
            }
            #pragma unroll
            for (int r = 0; r < 8; ++r)
                #pragma unroll
                for (int c = 0; c < TN; ++c)
                    acc[r][c] = fmaf(a[r], bb[c], acc[r][c]);
        }
    }

    const long pb = (long)blockIdx.y * 65536;
    #pragma unroll
    for (int r = 0; r < 8; ++r)
        #pragma unroll
        for (int c = 0; c < TN; ++c)
            part[pb + (tm * 8 + r) * 512 + n0 + tn * TN + c] = acc[r][c];
}

template<int NS>
__global__ __launch_bounds__(256)
void k_fc_reduce(const float* __restrict__ part, const float* __restrict__ bias,
                 float* __restrict__ H)
{
    const int f = (blockIdx.x * 256 + threadIdx.x) * 4;
    const int m = f >> 9, n = f & 511;
    float s0 = 0.f, s1 = 0.f, s2 = 0.f, s3 = 0.f;
    #pragma unroll 4
    for (int q = 0; q < NS; ++q) {
        const float* p = &part[(q * 128 + m) * 512 + n];
        s0 += p[0]; s1 += p[1]; s2 += p[2]; s3 += p[3];
    }
    H[f]     = fmaxf(s0 + bias[n],     0.f);
    H[f + 1] = fmaxf(s1 + bias[n + 1], 0.f);
    H[f + 2] = fmaxf(s2 + bias[n + 2], 0.f);
    H[f + 3] = fmaxf(s3 + bias[n + 3], 0.f);
}

// ---------------------------------------------------------------------------
// Final: FC3 + sampling + patch gather
// ---------------------------------------------------------------------------
__device__ __forceinline__ float softplusf(float x) {
    return (x > 20.f) ? x : log1pf(expf(x));
}
__device__ __forceinline__ float sigmoidf_(float x) {
    return 1.f / (1.f + expf(-x));
}

__global__ __launch_bounds__(256)
void k_final(const float* __restrict__ H2, const float* __restrict__ wl3,
             const float* __restrict__ bl3, const float* __restrict__ noise,
             const float* __restrict__ img, float* __restrict__ outp)
{
    __shared__ float h2[512];
    __shared__ float red[144];
    __shared__ float prep[36];
    __shared__ int ptsh[12], ptsw[12];
    const int b = blockIdx.x, t = threadIdx.x;

    h2[t]       = H2[b * 512 + t];
    h2[t + 256] = H2[b * 512 + 256 + t];
    __syncthreads();

    if (t < 144) {
        const int n = t >> 2, q = t & 3;
        float s = 0.f;
        for (int k = q * 128; k < q * 128 + 128; ++k)
            s = fmaf(h2[k], wl3[k * 36 + n], s);
        red[t] = s;
    }
    __syncthreads();
    if (t < 36)
        prep[t] = red[t * 4] + red[t * 4 + 1] + red[t * 4 + 2] + red[t * 4 + 3] + bl3[t];
    __syncthreads();

    if (t < 12) {
        const float m0 = prep[t * 3], m1 = prep[t * 3 + 1], sv = prep[t * 3 + 2];
        const float sig = softplusf(sv + 2.0f) * 128.f + 1e-7f;
        const float n0 = noise[(b * 12 + t) * 2], n1 = noise[(b * 12 + t) * 2 + 1];
        const float sa0 = m0 + sig * n0;
        const float sa1 = m1 + sig * n1;
        int p0 = (int)rintf(sigmoidf_(sa0) * 111.f);
        int p1 = (int)rintf(sigmoidf_(sa1) * 111.f);
        p0 = min(max(p0, 0), 111);
        p1 = min(max(p1, 0), 111);
        const int RM = 1179648;
        outp[RM        + (b * 12 + t) * 2 + 0] = m0;
        outp[RM        + (b * 12 + t) * 2 + 1] = m1;
        outp[RM + 3072 + (b * 12 + t) * 2 + 0] = sig;
        outp[RM + 3072 + (b * 12 + t) * 2 + 1] = sig;
        outp[RM + 6144 + (b * 12 + t) * 2 + 0] = sa0;
        outp[RM + 6144 + (b * 12 + t) * 2 + 1] = sa1;
        ptsh[t] = p0;
        ptsw[t] = p1;
    }
    __syncthreads();

    for (int i = t; i < 9216; i += 256) {
        const int g  = i / 768, r = i - g * 768;
        const int c  = r >> 8, r2 = r & 255;
        const int y  = r2 >> 4, x = r2 & 15;
        outp[b * 9216 + i] = img[((b * 3 + c) * 128 + ptsh[g] + y) * 128 + (ptsw[g] + x)];
    }
}

// ---------------------------------------------------------------------------
extern "C" void kernel_launch(void* const* d_in, const int* in_sizes, int n_in,
                              void* d_out, int out_size, void* d_ws, size_t ws_size,
                              hipStream_t stream)
{
    const float* img  = (const float*)d_in[0];
    const float* nois = (const float*)d_in[1];
    const float* w1 = (const float*)d_in[2];  const float* b1 = (const float*)d_in[3];
    const float* w2 = (const float*)d_in[4];  const float* b2 = (const float*)d_in[5];
    const float* w3 = (const float*)d_in[6];  const float* b3 = (const float*)d_in[7];
    const float* w4 = (const float*)d_in[8];  const float* b4 = (const float*)d_in[9];
    const float* w5 = (const float*)d_in[10]; const float* b5 = (const float*)d_in[11];
    const float* w6 = (const float*)d_in[12]; const float* b6 = (const float*)d_in[13];
    const float* wl1 = (const float*)d_in[14]; const float* bl1 = (const float*)d_in[15];
    const float* wl2 = (const float*)d_in[16]; const float* bl2 = (const float*)d_in[17];
    const float* wl3 = (const float*)d_in[18]; const float* bl3 = (const float*)d_in[19];
    float* out = (float*)d_out;
    float* ws  = (float*)d_ws;

    // workspace (float units). Activation regions span [0 .. 20971520).
    // Weight packs live ABOVE all activations (R6 bug: they were inside A4l).
    _Float16* P1h = (_Float16*)(ws);               // [128*32*32*32] halves
    _Float16* P1l = (_Float16*)(ws + 2097152);
    _Float16* A3h = (_Float16*)(ws + 4194304);     // [128*32*32*64]
    _Float16* A3l = (_Float16*)(ws + 8388608);
    _Float16* A4h = (_Float16*)(ws + 12582912);    // [128*32*32*64]
    _Float16* A4l = (_Float16*)(ws + 16777216);    // ..20971520
    _Float16* P2h = (_Float16*)(ws);               // [128*16*16*64] (P1 dead)
    _Float16* P2l = (_Float16*)(ws + 1048576);
    _Float16* A5h = (_Float16*)(ws + 4194304);     // [128*16*16*128] (A3 dead)
    _Float16* A5l = (_Float16*)(ws + 6291456);
    float* A6  = ws + 8388608;                     // [128*16*16*128] fp32 (A3 dead)
    float* FP1 = ws + 12582912;                    // [64][128][512] (A4h dead)
    float* H1  = ws + 16777216;                    // [128][512]     (A4l dead)
    float* FP2 = ws + 16842752;                    // [16][128][512]
    float* H2  = ws + 17891328;                    // [128][512]
    float* Wk2 = ws + 20971520;                    // [288][32] fp32, above all
    _Float16* Bh = (_Float16*)(ws + 20980736);     // 276480 halves
    _Float16* Bl = (_Float16*)(ws + 21118976);     // ends 21257216 fl = 85 MB

    hipLaunchKernelGGL(k_wrepackm, dim3(1116), dim3(256), 0, stream,
                       w2, w3, w4, w5, w6, Wk2, Bh, Bl);

    hipLaunchKernelGGL(k_conv12, dim3(32, 128), dim3(256), 0, stream,
                       img, w1, b1, Wk2, b2, P1h, P1l);
    // conv3: M=131072, K=288, COUT=64
    hipLaunchKernelGGL((k_mgemm<32, 64, 32, false>), dim3(1024, 1), dim3(256), 0, stream,
                       P1h, P1l, Bh + 0, Bl + 0, b3, A3h, A3l, nullptr);
    // conv4: K=576
    hipLaunchKernelGGL((k_mgemm<64, 64, 32, false>), dim3(1024, 1), dim3(256), 0, stream,
                       A3h, A3l, Bh + 18432, Bl + 18432, b4, A4h, A4l, nullptr);
    hipLaunchKernelGGL(k_pool2h, dim3(2048), dim3(256), 0, stream, A4h, A4l, P2h, P2l);
    // conv5: M=32768, K=576, COUT=128
    hipLaunchKernelGGL((k_mgemm<64, 128, 16, false>), dim3(256, 2), dim3(256), 0, stream,
                       P2h, P2l, Bh + 55296, Bl + 55296, b5, A5h, A5l, nullptr);
    // conv6: K=1152, fp32 out for FC1
    hipLaunchKernelGGL((k_mgemm<128, 128, 16, true>), dim3(256, 2), dim3(256), 0, stream,
                       A5h, A5l, Bh + 129024, Bl + 129024, b6, nullptr, nullptr, A6);
    hipLaunchKernelGGL((k_fc_partial<32768, 512, 4, true>), dim3(8, 64), dim3(256), 0, stream,
                       A6, wl1, FP1);
    hipLaunchKernelGGL(k_fc_reduce<64>, dim3(64), dim3(256), 0, stream, FP1, bl1, H1);
    hipLaunchKernelGGL((k_fc_partial<512, 32, 4, false>), dim3(8, 16), dim3(256), 0, stream,
                       H1, wl2, FP2);
    hipLaunchKernelGGL(k_fc_reduce<16>, dim3(64), dim3(256), 0, stream, FP2, bl2, H2);
    hipLaunchKernelGGL(k_final, dim3(128), dim3(256), 0, stream,
                       H2, wl3, bl3, nois, img, out);
}